// Round 2
// baseline (675.046 us; speedup 1.0000x reference)
//
#include <hip/hip_runtime.h>

#define NN 100000
#define EE 1600000

// ---------------- workspace layout (bytes) ----------------
// WC 0 | BC 81920 | Z0 82176 | ZA 16082176 | ZB 32082176 | DINV 48082176
// CNT 48482304 | PTR 48882432 | BSUM 49282560 | CROW 49284608 | CVAL 55684608
// total ~62.1 MB

__global__ void wc_kernel(const float* __restrict__ W1, const float* __restrict__ W2,
                          const float* __restrict__ b1, float* __restrict__ Wc,
                          float* __restrict__ bc) {
    int t = blockIdx.x * 256 + threadIdx.x;
    if (t < 512 * 40) {
        int k = t / 40, j = t - k * 40;
        float s = 0.f;
        for (int i = 0; i < 128; ++i) s = fmaf(W1[k * 128 + i], W2[i * 40 + j], s);
        Wc[t] = s;
    } else if (t < 512 * 40 + 40) {
        int j = t - 512 * 40;
        float s = 0.f;
        for (int i = 0; i < 128; ++i) s = fmaf(b1[i], W2[i * 40 + j], s);
        bc[j] = s;
    }
}

// z0 = x @ Wc + bc   (M=100000, K=512, N=40)
__global__ __launch_bounds__(256) void gemm_z0(const float* __restrict__ x,
                                               const float* __restrict__ Wc,
                                               const float* __restrict__ bc,
                                               float* __restrict__ z0) {
    __shared__ __align__(16) float xs[256 * 36];
    __shared__ __align__(16) float wsm[32 * 48];

    const int tid = threadIdx.x;
    const int rbase = blockIdx.x * 256;
    const int rg = tid >> 2, cg = tid & 3;
    const int r0 = rg * 4, j0 = cg * 12;

    float acc[4][12];
#pragma unroll
    for (int i = 0; i < 4; ++i)
#pragma unroll
        for (int j = 0; j < 12; ++j) acc[i][j] = 0.f;

    for (int kt = 0; kt < 16; ++kt) {
        const int k0 = kt * 32;
#pragma unroll
        for (int i = 0; i < 8; ++i) {
            int f = i * 256 + tid;
            int row = f >> 3, kq = f & 7;
            float4 v = make_float4(0.f, 0.f, 0.f, 0.f);
            int grow = rbase + row;
            if (grow < NN)
                v = *reinterpret_cast<const float4*>(x + (size_t)grow * 512 + k0 + kq * 4);
            *reinterpret_cast<float4*>(&xs[row * 36 + kq * 4]) = v;
        }
#pragma unroll
        for (int i = 0; i < 5; ++i) {
            int f = i * 256 + tid;
            int k = f / 40, j = f - k * 40;
            wsm[k * 48 + j] = Wc[k0 * 40 + f];
        }
        { int k = tid >> 3, j = 40 + (tid & 7); wsm[k * 48 + j] = 0.f; }
        __syncthreads();

#pragma unroll 4
        for (int k = 0; k < 32; ++k) {
            float a0 = xs[(r0 + 0) * 36 + k];
            float a1 = xs[(r0 + 1) * 36 + k];
            float a2 = xs[(r0 + 2) * 36 + k];
            float a3 = xs[(r0 + 3) * 36 + k];
            float4 w0 = *reinterpret_cast<const float4*>(&wsm[k * 48 + j0]);
            float4 w1 = *reinterpret_cast<const float4*>(&wsm[k * 48 + j0 + 4]);
            float4 w2 = *reinterpret_cast<const float4*>(&wsm[k * 48 + j0 + 8]);
            float w[12] = {w0.x, w0.y, w0.z, w0.w, w1.x, w1.y, w1.z, w1.w,
                           w2.x, w2.y, w2.z, w2.w};
#pragma unroll
            for (int j = 0; j < 12; ++j) {
                acc[0][j] = fmaf(a0, w[j], acc[0][j]);
                acc[1][j] = fmaf(a1, w[j], acc[1][j]);
                acc[2][j] = fmaf(a2, w[j], acc[2][j]);
                acc[3][j] = fmaf(a3, w[j], acc[3][j]);
            }
        }
        __syncthreads();
    }

#pragma unroll
    for (int i = 0; i < 4; ++i) {
        int row = rbase + r0 + i;
        if (row < NN) {
#pragma unroll
            for (int q = 0; q < 3; ++q) {
                int col = j0 + q * 4;
                if (col < 40) {
                    float4 o;
                    o.x = acc[i][q * 4 + 0] + bc[col + 0];
                    o.y = acc[i][q * 4 + 1] + bc[col + 1];
                    o.z = acc[i][q * 4 + 2] + bc[col + 2];
                    o.w = acc[i][q * 4 + 3] + bc[col + 3];
                    *reinterpret_cast<float4*>(z0 + (size_t)row * 40 + col) = o;
                }
            }
        }
    }
}

__global__ void count_kernel(const int* __restrict__ eidx, int* __restrict__ counts) {
    int e = blockIdx.x * 256 + threadIdx.x;
    if (e < EE) atomicAdd(&counts[eidx[EE + e]], 1);
}

__global__ void scan1(const int* __restrict__ counts, int* __restrict__ ptr,
                      int* __restrict__ bsum) {
    __shared__ int s[256];
    int tid = threadIdx.x;
    int i = blockIdx.x * 256 + tid;
    int v = (i < NN) ? counts[i] : 0;
    s[tid] = v;
    __syncthreads();
    for (int off = 1; off < 256; off <<= 1) {
        int t = (tid >= off) ? s[tid - off] : 0;
        __syncthreads();
        s[tid] += t;
        __syncthreads();
    }
    if (i < NN) ptr[i] = s[tid] - v;
    if (tid == 255) bsum[blockIdx.x] = s[255];
}

__global__ void scan2(int* __restrict__ bsum) {
    __shared__ int s[512];
    int tid = threadIdx.x;
    int v = (tid < 391) ? bsum[tid] : 0;
    s[tid] = v;
    __syncthreads();
    for (int off = 1; off < 512; off <<= 1) {
        int t = (tid >= off) ? s[tid - off] : 0;
        __syncthreads();
        s[tid] += t;
        __syncthreads();
    }
    if (tid < 391) bsum[tid] = s[tid] - v;
}

__global__ void scan3(int* __restrict__ ptr, const int* __restrict__ bsum) {
    int i = blockIdx.x * 256 + threadIdx.x;
    if (i < NN) ptr[i] += bsum[blockIdx.x];
    if (i == 0) ptr[NN] = EE;
}

__global__ void dinv_kernel(const int* __restrict__ counts, float* __restrict__ dinvp) {
    int i = blockIdx.x * 256 + threadIdx.x;
    if (i < NN) dinvp[i] = rsqrtf(1.0f + (float)counts[i]);
}

__global__ void scatter_kernel(const int* __restrict__ eidx, const int* __restrict__ ptr,
                               const float* __restrict__ dinvp, int* __restrict__ cursor,
                               int* __restrict__ crow, float* __restrict__ cval) {
    int e = blockIdx.x * 256 + threadIdx.x;
    if (e < EE) {
        int r = eidx[e];
        int c = eidx[EE + e];
        int pos = ptr[c] + atomicAdd(&cursor[c], 1);
        crow[pos] = r;
        cval[pos] = dinvp[r];
    }
}

__global__ __launch_bounds__(256) void propagate(const float* __restrict__ zcur,
                                                 const float* __restrict__ z0,
                                                 float* __restrict__ znext,
                                                 const int* __restrict__ ptr,
                                                 const int* __restrict__ crow,
                                                 const float* __restrict__ cval,
                                                 const float* __restrict__ dinvp,
                                                 const float* __restrict__ b2, int addbias) {
    int wave = threadIdx.x >> 6;
    int lane = threadIdx.x & 63;
    int node = blockIdx.x * 4 + wave;
    if (node >= NN) return;
    int jc = lane < 40 ? lane : 39;

    int beg = ptr[node], end = ptr[node + 1];
    float dc = dinvp[node];
    float acc = dc * zcur[(size_t)node * 40 + jc];

    int e = beg;
    for (; e + 4 <= end; e += 4) {
        int r0 = crow[e + 0], r1 = crow[e + 1], r2 = crow[e + 2], r3 = crow[e + 3];
        float v0 = cval[e + 0], v1 = cval[e + 1], v2 = cval[e + 2], v3 = cval[e + 3];
        float x0 = zcur[(size_t)r0 * 40 + jc];
        float x1 = zcur[(size_t)r1 * 40 + jc];
        float x2 = zcur[(size_t)r2 * 40 + jc];
        float x3 = zcur[(size_t)r3 * 40 + jc];
        acc = fmaf(v0, x0, acc);
        acc = fmaf(v1, x1, acc);
        acc = fmaf(v2, x2, acc);
        acc = fmaf(v3, x3, acc);
    }
    for (; e < end; ++e) acc = fmaf(cval[e], zcur[(size_t)crow[e] * 40 + jc], acc);

    float res = 0.5f * dc * acc + 0.5f * z0[(size_t)node * 40 + jc];
    if (addbias) res += b2[jc];
    if (lane < 40) znext[(size_t)node * 40 + lane] = res;
}

extern "C" void kernel_launch(void* const* d_in, const int* in_sizes, int n_in,
                              void* d_out, int out_size, void* d_ws, size_t ws_size,
                              hipStream_t stream) {
    const float* x  = (const float*)d_in[0];
    const int*   ei = (const int*)d_in[1];
    const float* W1 = (const float*)d_in[2];
    const float* b1 = (const float*)d_in[3];
    const float* W2 = (const float*)d_in[4];
    const float* b2 = (const float*)d_in[5];
    float* out = (float*)d_out;

    char* ws = (char*)d_ws;
    float* Wc   = (float*)(ws + 0);
    float* bc   = (float*)(ws + 81920);
    float* z0   = (float*)(ws + 82176);
    float* za   = (float*)(ws + 16082176);
    float* zb   = (float*)(ws + 32082176);
    float* dinv = (float*)(ws + 48082176);
    int*   cnt  = (int*)(ws + 48482304);
    int*   ptr  = (int*)(ws + 48882432);
    int*   bsum = (int*)(ws + 49282560);
    int*   crow = (int*)(ws + 49284608);
    float* cval = (float*)(ws + 55684608);

    hipMemsetAsync(cnt, 0, NN * sizeof(int), stream);
    wc_kernel<<<81, 256, 0, stream>>>(W1, W2, b1, Wc, bc);
    count_kernel<<<(EE + 255) / 256, 256, 0, stream>>>(ei, cnt);
    scan1<<<391, 256, 0, stream>>>(cnt, ptr, bsum);
    scan2<<<1, 512, 0, stream>>>(bsum);
    scan3<<<391, 256, 0, stream>>>(ptr, bsum);
    dinv_kernel<<<391, 256, 0, stream>>>(cnt, dinv);
    gemm_z0<<<391, 256, 0, stream>>>(x, Wc, bc, z0);
    hipMemsetAsync(cnt, 0, NN * sizeof(int), stream);
    scatter_kernel<<<(EE + 255) / 256, 256, 0, stream>>>(ei, ptr, dinv, cnt, crow, cval);

    propagate<<<25000, 256, 0, stream>>>(z0, z0, zb, ptr, crow, cval, dinv, b2, 0);
    propagate<<<25000, 256, 0, stream>>>(zb, z0, za, ptr, crow, cval, dinv, b2, 0);
    propagate<<<25000, 256, 0, stream>>>(za, z0, zb, ptr, crow, cval, dinv, b2, 0);
    propagate<<<25000, 256, 0, stream>>>(zb, z0, za, ptr, crow, cval, dinv, b2, 0);
    propagate<<<25000, 256, 0, stream>>>(za, z0, out, ptr, crow, cval, dinv, b2, 1);
}

// Round 3
// 529.358 us; speedup vs baseline: 1.2752x; 1.2752x over previous
//
#include <hip/hip_runtime.h>
#include <hip/hip_bf16.h>

#define NN 100000
#define EE 1600000

typedef __attribute__((ext_vector_type(8))) short short8;
typedef __attribute__((ext_vector_type(4))) float f32x4;

__device__ __forceinline__ short f2bf(float f) {
    __hip_bfloat16 h = __float2bfloat16(f);
    return *reinterpret_cast<short*>(&h);
}

// ---------------- workspace layout (bytes) ----------------
// WCT 0 (49152) | BC 49152 (192) | Z0 65536 | ZA 16065536 | ZB 32065536
// DINV 48065536 | CNT 48465536 | PTR 48865536 | BSUM 49265664 | CEV 49267712
// total 62,067,712 B

// WcT[j][k] = bf16( (W1@W2)[k][j] ), j padded to 48 with zeros; bc = b1@W2 (48, pad 0)
__global__ void wct_kernel(const float* __restrict__ W1, const float* __restrict__ W2,
                           const float* __restrict__ b1, short* __restrict__ WcT,
                           float* __restrict__ bc) {
    int t = blockIdx.x * 256 + threadIdx.x;
    if (t < 48 * 512) {
        int j = t >> 9, k = t & 511;
        float s = 0.f;
        if (j < 40)
            for (int i = 0; i < 128; ++i) s = fmaf(W1[k * 128 + i], W2[i * 40 + j], s);
        WcT[j * 512 + k] = f2bf(s);
    } else if (t < 48 * 512 + 48) {
        int j = t - 48 * 512;
        float s = 0.f;
        if (j < 40)
            for (int i = 0; i < 128; ++i) s = fmaf(b1[i], W2[i * 40 + j], s);
        bc[j] = s;
    }
}

// z0 = x @ Wc + bc via MFMA, A-frags straight from global x (f32->bf16 in-reg),
// B-frags straight from L2-resident WcT. Block = 4 waves x 16 rows = 64 rows.
__global__ __launch_bounds__(256) void gemm_z0(const float* __restrict__ x,
                                               const short* __restrict__ WcT,
                                               const float* __restrict__ bc,
                                               float* __restrict__ z0) {
    const int tid = threadIdx.x;
    const int lane = tid & 63;
    const int wave = tid >> 6;
    const int rbase = blockIdx.x * 64 + wave * 16;
    const int row = rbase + (lane & 15);
    const int kc = lane >> 4;  // 0..3
    const bool rok = row < NN;

    f32x4 acc0 = {0.f, 0.f, 0.f, 0.f};
    f32x4 acc1 = {0.f, 0.f, 0.f, 0.f};
    f32x4 acc2 = {0.f, 0.f, 0.f, 0.f};

    const float* xrow = x + (size_t)row * 512 + kc * 8;
    const short* bp0 = WcT + (size_t)(lane & 15) * 512 + kc * 8;
    const short* bp1 = bp0 + 16 * 512;
    const short* bp2 = bp0 + 32 * 512;

    for (int k0 = 0; k0 < 512; k0 += 32) {
        float4 p0 = {0.f, 0.f, 0.f, 0.f}, p1 = {0.f, 0.f, 0.f, 0.f};
        if (rok) {
            p0 = *reinterpret_cast<const float4*>(xrow + k0);
            p1 = *reinterpret_cast<const float4*>(xrow + k0 + 4);
        }
        short8 a;
        a[0] = f2bf(p0.x); a[1] = f2bf(p0.y); a[2] = f2bf(p0.z); a[3] = f2bf(p0.w);
        a[4] = f2bf(p1.x); a[5] = f2bf(p1.y); a[6] = f2bf(p1.z); a[7] = f2bf(p1.w);
        short8 b0 = *reinterpret_cast<const short8*>(bp0 + k0);
        short8 b1 = *reinterpret_cast<const short8*>(bp1 + k0);
        short8 b2 = *reinterpret_cast<const short8*>(bp2 + k0);
        acc0 = __builtin_amdgcn_mfma_f32_16x16x32_bf16(a, b0, acc0, 0, 0, 0);
        acc1 = __builtin_amdgcn_mfma_f32_16x16x32_bf16(a, b1, acc1, 0, 0, 0);
        acc2 = __builtin_amdgcn_mfma_f32_16x16x32_bf16(a, b2, acc2, 0, 0, 0);
    }

    // C/D layout: col = lane&15, row = (lane>>4)*4 + q   [m89/m91 verified]
    const int cb = lane & 15;
    const int rr = rbase + (lane >> 4) * 4;
#pragma unroll
    for (int q = 0; q < 4; ++q) {
        int r = rr + q;
        if (r < NN) {
            z0[(size_t)r * 40 + cb] = acc0[q] + bc[cb];
            z0[(size_t)r * 40 + cb + 16] = acc1[q] + bc[cb + 16];
            if (cb + 32 < 40) z0[(size_t)r * 40 + cb + 32] = acc2[q] + bc[cb + 32];
        }
    }
}

__global__ void count_kernel(const int* __restrict__ eidx, int* __restrict__ counts) {
    int e = blockIdx.x * 256 + threadIdx.x;
    if (e < EE) atomicAdd(&counts[eidx[EE + e]], 1);
}

__global__ void scan1(const int* __restrict__ counts, int* __restrict__ ptr,
                      int* __restrict__ bsum) {
    __shared__ int s[256];
    int tid = threadIdx.x;
    int i = blockIdx.x * 256 + tid;
    int v = (i < NN) ? counts[i] : 0;
    s[tid] = v;
    __syncthreads();
    for (int off = 1; off < 256; off <<= 1) {
        int t = (tid >= off) ? s[tid - off] : 0;
        __syncthreads();
        s[tid] += t;
        __syncthreads();
    }
    if (i < NN) ptr[i] = s[tid] - v;
    if (tid == 255) bsum[blockIdx.x] = s[255];
}

__global__ void scan2(int* __restrict__ bsum) {
    __shared__ int s[512];
    int tid = threadIdx.x;
    int v = (tid < 391) ? bsum[tid] : 0;
    s[tid] = v;
    __syncthreads();
    for (int off = 1; off < 512; off <<= 1) {
        int t = (tid >= off) ? s[tid - off] : 0;
        __syncthreads();
        s[tid] += t;
        __syncthreads();
    }
    if (tid < 391) bsum[tid] = s[tid] - v;
}

__global__ void scan3(int* __restrict__ ptr, const int* __restrict__ bsum) {
    int i = blockIdx.x * 256 + threadIdx.x;
    if (i < NN) ptr[i] += bsum[blockIdx.x];
    if (i == 0) ptr[NN] = EE;
}

__global__ void dinv_kernel(const int* __restrict__ counts, float* __restrict__ dinvp) {
    int i = blockIdx.x * 256 + threadIdx.x;
    if (i < NN) dinvp[i] = rsqrtf(1.0f + (float)counts[i]);
}

// bucket edges by target: cev[pos] = (row, bitcast(dinv[row]))
__global__ void scatter_kernel(const int* __restrict__ eidx, const int* __restrict__ ptr,
                               const float* __restrict__ dinvp, int* __restrict__ cursor,
                               int2* __restrict__ cev) {
    int e = blockIdx.x * 256 + threadIdx.x;
    if (e < EE) {
        int r = eidx[e];
        int c = eidx[EE + e];
        int pos = ptr[c] + atomicAdd(&cursor[c], 1);
        cev[pos] = make_int2(r, __float_as_int(dinvp[r]));
    }
}

// one wave per node; cooperative edge-block load + v_readlane broadcast
__global__ __launch_bounds__(256) void propagate(const float* __restrict__ zcur,
                                                 const float* __restrict__ z0,
                                                 float* __restrict__ znext,
                                                 const int* __restrict__ ptr,
                                                 const int2* __restrict__ cev,
                                                 const float* __restrict__ dinvp,
                                                 const float* __restrict__ b2, int addbias) {
    int wave = threadIdx.x >> 6;
    int lane = threadIdx.x & 63;
    int node = blockIdx.x * 4 + wave;
    if (node >= NN) return;
    int jc = lane < 40 ? lane : 39;

    int beg = ptr[node], end = ptr[node + 1];
    float dc = dinvp[node];
    float acc = dc * zcur[(size_t)node * 40 + jc];

    int e = beg;
    while (e < end) {
        int m = end - e;
        if (m > 64) m = 64;
        int2 ev = cev[e + (lane < m ? lane : m - 1)];
        int rl = ev.x;
        int vl = ev.y;
        int j = 0;
        for (; j + 4 <= m; j += 4) {
            int r0 = __builtin_amdgcn_readlane(rl, j + 0);
            int r1 = __builtin_amdgcn_readlane(rl, j + 1);
            int r2 = __builtin_amdgcn_readlane(rl, j + 2);
            int r3 = __builtin_amdgcn_readlane(rl, j + 3);
            float v0 = __int_as_float(__builtin_amdgcn_readlane(vl, j + 0));
            float v1 = __int_as_float(__builtin_amdgcn_readlane(vl, j + 1));
            float v2 = __int_as_float(__builtin_amdgcn_readlane(vl, j + 2));
            float v3 = __int_as_float(__builtin_amdgcn_readlane(vl, j + 3));
            float x0 = zcur[(size_t)r0 * 40 + jc];
            float x1 = zcur[(size_t)r1 * 40 + jc];
            float x2 = zcur[(size_t)r2 * 40 + jc];
            float x3 = zcur[(size_t)r3 * 40 + jc];
            acc = fmaf(v0, x0, acc);
            acc = fmaf(v1, x1, acc);
            acc = fmaf(v2, x2, acc);
            acc = fmaf(v3, x3, acc);
        }
        for (; j < m; ++j) {
            int r = __builtin_amdgcn_readlane(rl, j);
            float v = __int_as_float(__builtin_amdgcn_readlane(vl, j));
            acc = fmaf(v, zcur[(size_t)r * 40 + jc], acc);
        }
        e += m;
    }

    float res = 0.5f * dc * acc + 0.5f * z0[(size_t)node * 40 + jc];
    if (addbias) res += b2[jc];
    if (lane < 40) znext[(size_t)node * 40 + lane] = res;
}

extern "C" void kernel_launch(void* const* d_in, const int* in_sizes, int n_in,
                              void* d_out, int out_size, void* d_ws, size_t ws_size,
                              hipStream_t stream) {
    const float* x  = (const float*)d_in[0];
    const int*   ei = (const int*)d_in[1];
    const float* W1 = (const float*)d_in[2];
    const float* b1 = (const float*)d_in[3];
    const float* W2 = (const float*)d_in[4];
    const float* b2 = (const float*)d_in[5];
    float* out = (float*)d_out;

    char* ws = (char*)d_ws;
    short* WcT  = (short*)(ws + 0);
    float* bc   = (float*)(ws + 49152);
    float* z0   = (float*)(ws + 65536);
    float* za   = (float*)(ws + 16065536);
    float* zb   = (float*)(ws + 32065536);
    float* dinv = (float*)(ws + 48065536);
    int*   cnt  = (int*)(ws + 48465536);
    int*   ptr  = (int*)(ws + 48865536);
    int*   bsum = (int*)(ws + 49265664);
    int2*  cev  = (int2*)(ws + 49267712);

    hipMemsetAsync(cnt, 0, NN * sizeof(int), stream);
    wct_kernel<<<97, 256, 0, stream>>>(W1, W2, b1, WcT, bc);
    count_kernel<<<(EE + 255) / 256, 256, 0, stream>>>(ei, cnt);
    scan1<<<391, 256, 0, stream>>>(cnt, ptr, bsum);
    scan2<<<1, 512, 0, stream>>>(bsum);
    scan3<<<391, 256, 0, stream>>>(ptr, bsum);
    dinv_kernel<<<391, 256, 0, stream>>>(cnt, dinv);
    gemm_z0<<<1563, 256, 0, stream>>>(x, WcT, bc, z0);
    hipMemsetAsync(cnt, 0, NN * sizeof(int), stream);
    scatter_kernel<<<(EE + 255) / 256, 256, 0, stream>>>(ei, ptr, dinv, cnt, cev);

    propagate<<<25000, 256, 0, stream>>>(z0, z0, zb, ptr, cev, dinv, b2, 0);
    propagate<<<25000, 256, 0, stream>>>(zb, z0, za, ptr, cev, dinv, b2, 0);
    propagate<<<25000, 256, 0, stream>>>(za, z0, zb, ptr, cev, dinv, b2, 0);
    propagate<<<25000, 256, 0, stream>>>(zb, z0, za, ptr, cev, dinv, b2, 0);
    propagate<<<25000, 256, 0, stream>>>(za, z0, out, ptr, cev, dinv, b2, 1);
}

// Round 4
// 499.069 us; speedup vs baseline: 1.3526x; 1.0607x over previous
//
#include <hip/hip_runtime.h>
#include <hip/hip_bf16.h>

#define NN 100000
#define EE 1600000

typedef __attribute__((ext_vector_type(8))) short short8;
typedef __attribute__((ext_vector_type(4))) float f32x4;

__device__ __forceinline__ short f2bf(float f) {
    __hip_bfloat16 h = __float2bfloat16(f);
    return *reinterpret_cast<short*>(&h);
}
__device__ __forceinline__ float bf2f(unsigned short u) {
    return __uint_as_float((unsigned int)u << 16);
}

// ---------------- workspace layout (bytes) ----------------
// WCT 0 (49152) | BC 49152 | Z0 65536 (8e6) | ZA 8065536 | ZB 16065536
// DINV 24065536 | CNT 24465664 | PTR 24865792 | BSUM 25265920 | CEV 25267968
// total ~38.1 MB

__global__ void wct_kernel(const float* __restrict__ W1, const float* __restrict__ W2,
                           const float* __restrict__ b1, short* __restrict__ WcT,
                           float* __restrict__ bc) {
    int t = blockIdx.x * 256 + threadIdx.x;
    if (t < 48 * 512) {
        int j = t >> 9, k = t & 511;
        float s = 0.f;
        if (j < 40)
            for (int i = 0; i < 128; ++i) s = fmaf(W1[k * 128 + i], W2[i * 40 + j], s);
        WcT[j * 512 + k] = f2bf(s);
    } else if (t < 48 * 512 + 48) {
        int j = t - 48 * 512;
        float s = 0.f;
        if (j < 40)
            for (int i = 0; i < 128; ++i) s = fmaf(b1[i], W2[i * 40 + j], s);
        bc[j] = s;
    }
}

// z0 = bf16( x @ Wc + bc ) via MFMA, A-frags straight from global x.
__global__ __launch_bounds__(256) void gemm_z0(const float* __restrict__ x,
                                               const short* __restrict__ WcT,
                                               const float* __restrict__ bc,
                                               unsigned short* __restrict__ z0) {
    const int tid = threadIdx.x;
    const int lane = tid & 63;
    const int wave = tid >> 6;
    const int rbase = blockIdx.x * 64 + wave * 16;
    const int row = rbase + (lane & 15);
    const int kc = lane >> 4;
    const bool rok = row < NN;

    f32x4 acc0 = {0.f, 0.f, 0.f, 0.f};
    f32x4 acc1 = {0.f, 0.f, 0.f, 0.f};
    f32x4 acc2 = {0.f, 0.f, 0.f, 0.f};

    const float* xrow = x + (size_t)row * 512 + kc * 8;
    const short* bp0 = WcT + (size_t)(lane & 15) * 512 + kc * 8;
    const short* bp1 = bp0 + 16 * 512;
    const short* bp2 = bp0 + 32 * 512;

    for (int k0 = 0; k0 < 512; k0 += 32) {
        float4 p0 = {0.f, 0.f, 0.f, 0.f}, p1 = {0.f, 0.f, 0.f, 0.f};
        if (rok) {
            p0 = *reinterpret_cast<const float4*>(xrow + k0);
            p1 = *reinterpret_cast<const float4*>(xrow + k0 + 4);
        }
        short8 a;
        a[0] = f2bf(p0.x); a[1] = f2bf(p0.y); a[2] = f2bf(p0.z); a[3] = f2bf(p0.w);
        a[4] = f2bf(p1.x); a[5] = f2bf(p1.y); a[6] = f2bf(p1.z); a[7] = f2bf(p1.w);
        short8 b0 = *reinterpret_cast<const short8*>(bp0 + k0);
        short8 b1 = *reinterpret_cast<const short8*>(bp1 + k0);
        short8 b2 = *reinterpret_cast<const short8*>(bp2 + k0);
        acc0 = __builtin_amdgcn_mfma_f32_16x16x32_bf16(a, b0, acc0, 0, 0, 0);
        acc1 = __builtin_amdgcn_mfma_f32_16x16x32_bf16(a, b1, acc1, 0, 0, 0);
        acc2 = __builtin_amdgcn_mfma_f32_16x16x32_bf16(a, b2, acc2, 0, 0, 0);
    }

    const int cb = lane & 15;
    const int rr = rbase + (lane >> 4) * 4;
#pragma unroll
    for (int q = 0; q < 4; ++q) {
        int r = rr + q;
        if (r < NN) {
            z0[(size_t)r * 40 + cb] = (unsigned short)f2bf(acc0[q] + bc[cb]);
            z0[(size_t)r * 40 + cb + 16] = (unsigned short)f2bf(acc1[q] + bc[cb + 16]);
            if (cb + 32 < 40)
                z0[(size_t)r * 40 + cb + 32] = (unsigned short)f2bf(acc2[q] + bc[cb + 32]);
        }
    }
}

__global__ void count_kernel(const int* __restrict__ eidx, int* __restrict__ counts) {
    int e = blockIdx.x * 256 + threadIdx.x;
    if (e < EE) atomicAdd(&counts[eidx[EE + e]], 1);
}

__global__ void scan1(const int* __restrict__ counts, int* __restrict__ ptr,
                      int* __restrict__ bsum) {
    __shared__ int s[256];
    int tid = threadIdx.x;
    int i = blockIdx.x * 256 + tid;
    int v = (i < NN) ? counts[i] : 0;
    s[tid] = v;
    __syncthreads();
    for (int off = 1; off < 256; off <<= 1) {
        int t = (tid >= off) ? s[tid - off] : 0;
        __syncthreads();
        s[tid] += t;
        __syncthreads();
    }
    if (i < NN) ptr[i] = s[tid] - v;
    if (tid == 255) bsum[blockIdx.x] = s[255];
}

__global__ void scan2(int* __restrict__ bsum) {
    __shared__ int s[512];
    int tid = threadIdx.x;
    int v = (tid < 391) ? bsum[tid] : 0;
    s[tid] = v;
    __syncthreads();
    for (int off = 1; off < 512; off <<= 1) {
        int t = (tid >= off) ? s[tid - off] : 0;
        __syncthreads();
        s[tid] += t;
        __syncthreads();
    }
    if (tid < 391) bsum[tid] = s[tid] - v;
}

__global__ void scan3(int* __restrict__ ptr, const int* __restrict__ bsum) {
    int i = blockIdx.x * 256 + threadIdx.x;
    if (i < NN) ptr[i] += bsum[blockIdx.x];
    if (i == 0) ptr[NN] = EE;
}

__global__ void dinv_kernel(const int* __restrict__ counts, float* __restrict__ dinvp) {
    int i = blockIdx.x * 256 + threadIdx.x;
    if (i < NN) dinvp[i] = rsqrtf(1.0f + (float)counts[i]);
}

__global__ void scatter_kernel(const int* __restrict__ eidx, const int* __restrict__ ptr,
                               const float* __restrict__ dinvp, int* __restrict__ cursor,
                               int2* __restrict__ cev) {
    int e = blockIdx.x * 256 + threadIdx.x;
    if (e < EE) {
        int r = eidx[e];
        int c = eidx[EE + e];
        int pos = ptr[c] + atomicAdd(&cursor[c], 1);
        cev[pos] = make_int2(r, __float_as_int(dinvp[r]));
    }
}

// one wave per node; bf16 state, 8-deep gather unroll, two FMA chains
__global__ __launch_bounds__(256) void propagate(const unsigned short* __restrict__ zcur,
                                                 const unsigned short* __restrict__ z0q,
                                                 unsigned short* __restrict__ znb,
                                                 float* __restrict__ outf,
                                                 const int* __restrict__ ptr,
                                                 const int2* __restrict__ cev,
                                                 const float* __restrict__ dinvp,
                                                 const float* __restrict__ b2, int last) {
    int wave = threadIdx.x >> 6;
    int lane = threadIdx.x & 63;
    int node = blockIdx.x * 4 + wave;
    if (node >= NN) return;
    int jc = lane < 40 ? lane : 39;

    int beg = ptr[node], end = ptr[node + 1];
    float dc = dinvp[node];
    float acc = dc * bf2f(zcur[(size_t)node * 40 + jc]);
    float acc2 = 0.f;

    int e = beg;
    while (e < end) {
        int m = end - e;
        if (m > 64) m = 64;
        int2 ev = cev[e + (lane < m ? lane : m - 1)];
        int rl = ev.x;
        int vl = ev.y;
        int j = 0;
        for (; j + 8 <= m; j += 8) {
            int r0 = __builtin_amdgcn_readlane(rl, j + 0);
            int r1 = __builtin_amdgcn_readlane(rl, j + 1);
            int r2 = __builtin_amdgcn_readlane(rl, j + 2);
            int r3 = __builtin_amdgcn_readlane(rl, j + 3);
            int r4 = __builtin_amdgcn_readlane(rl, j + 4);
            int r5 = __builtin_amdgcn_readlane(rl, j + 5);
            int r6 = __builtin_amdgcn_readlane(rl, j + 6);
            int r7 = __builtin_amdgcn_readlane(rl, j + 7);
            float x0 = bf2f(zcur[(size_t)r0 * 40 + jc]);
            float x1 = bf2f(zcur[(size_t)r1 * 40 + jc]);
            float x2 = bf2f(zcur[(size_t)r2 * 40 + jc]);
            float x3 = bf2f(zcur[(size_t)r3 * 40 + jc]);
            float x4 = bf2f(zcur[(size_t)r4 * 40 + jc]);
            float x5 = bf2f(zcur[(size_t)r5 * 40 + jc]);
            float x6 = bf2f(zcur[(size_t)r6 * 40 + jc]);
            float x7 = bf2f(zcur[(size_t)r7 * 40 + jc]);
            float v0 = __int_as_float(__builtin_amdgcn_readlane(vl, j + 0));
            float v1 = __int_as_float(__builtin_amdgcn_readlane(vl, j + 1));
            float v2 = __int_as_float(__builtin_amdgcn_readlane(vl, j + 2));
            float v3 = __int_as_float(__builtin_amdgcn_readlane(vl, j + 3));
            float v4 = __int_as_float(__builtin_amdgcn_readlane(vl, j + 4));
            float v5 = __int_as_float(__builtin_amdgcn_readlane(vl, j + 5));
            float v6 = __int_as_float(__builtin_amdgcn_readlane(vl, j + 6));
            float v7 = __int_as_float(__builtin_amdgcn_readlane(vl, j + 7));
            acc = fmaf(v0, x0, acc);
            acc2 = fmaf(v1, x1, acc2);
            acc = fmaf(v2, x2, acc);
            acc2 = fmaf(v3, x3, acc2);
            acc = fmaf(v4, x4, acc);
            acc2 = fmaf(v5, x5, acc2);
            acc = fmaf(v6, x6, acc);
            acc2 = fmaf(v7, x7, acc2);
        }
        for (; j < m; ++j) {
            int r = __builtin_amdgcn_readlane(rl, j);
            float v = __int_as_float(__builtin_amdgcn_readlane(vl, j));
            acc = fmaf(v, bf2f(zcur[(size_t)r * 40 + jc]), acc);
        }
        e += m;
    }

    float res = 0.5f * dc * (acc + acc2) + 0.5f * bf2f(z0q[(size_t)node * 40 + jc]);
    if (lane < 40) {
        if (last)
            outf[(size_t)node * 40 + lane] = res + b2[lane];
        else
            znb[(size_t)node * 40 + lane] = (unsigned short)f2bf(res);
    }
}

extern "C" void kernel_launch(void* const* d_in, const int* in_sizes, int n_in,
                              void* d_out, int out_size, void* d_ws, size_t ws_size,
                              hipStream_t stream) {
    const float* x  = (const float*)d_in[0];
    const int*   ei = (const int*)d_in[1];
    const float* W1 = (const float*)d_in[2];
    const float* b1 = (const float*)d_in[3];
    const float* W2 = (const float*)d_in[4];
    const float* b2 = (const float*)d_in[5];
    float* out = (float*)d_out;

    char* ws = (char*)d_ws;
    short*          WcT  = (short*)(ws + 0);
    float*          bc   = (float*)(ws + 49152);
    unsigned short* z0   = (unsigned short*)(ws + 65536);
    unsigned short* za   = (unsigned short*)(ws + 8065536);
    unsigned short* zb   = (unsigned short*)(ws + 16065536);
    float*          dinv = (float*)(ws + 24065536);
    int*            cnt  = (int*)(ws + 24465664);
    int*            ptr  = (int*)(ws + 24865792);
    int*            bsum = (int*)(ws + 25265920);
    int2*           cev  = (int2*)(ws + 25267968);

    hipMemsetAsync(cnt, 0, NN * sizeof(int), stream);
    wct_kernel<<<97, 256, 0, stream>>>(W1, W2, b1, WcT, bc);
    count_kernel<<<(EE + 255) / 256, 256, 0, stream>>>(ei, cnt);
    scan1<<<391, 256, 0, stream>>>(cnt, ptr, bsum);
    scan2<<<1, 512, 0, stream>>>(bsum);
    scan3<<<391, 256, 0, stream>>>(ptr, bsum);
    dinv_kernel<<<391, 256, 0, stream>>>(cnt, dinv);
    gemm_z0<<<1563, 256, 0, stream>>>(x, WcT, bc, z0);
    hipMemsetAsync(cnt, 0, NN * sizeof(int), stream);
    scatter_kernel<<<(EE + 255) / 256, 256, 0, stream>>>(ei, ptr, dinv, cnt, cev);

    propagate<<<25000, 256, 0, stream>>>(z0, z0, zb, out, ptr, cev, dinv, b2, 0);
    propagate<<<25000, 256, 0, stream>>>(zb, z0, za, out, ptr, cev, dinv, b2, 0);
    propagate<<<25000, 256, 0, stream>>>(za, z0, zb, out, ptr, cev, dinv, b2, 0);
    propagate<<<25000, 256, 0, stream>>>(zb, z0, za, out, ptr, cev, dinv, b2, 0);
    propagate<<<25000, 256, 0, stream>>>(za, z0, zb, out, ptr, cev, dinv, b2, 1);
}

// Round 5
// 469.295 us; speedup vs baseline: 1.4384x; 1.0634x over previous
//
#include <hip/hip_runtime.h>
#include <hip/hip_bf16.h>

#define NN 100000
#define EE 1600000
#define HALFN 50000

typedef __attribute__((ext_vector_type(8))) short short8;
typedef __attribute__((ext_vector_type(4))) float f32x4;

__device__ __forceinline__ short f2bf(float f) {
    __hip_bfloat16 h = __float2bfloat16(f);
    return *reinterpret_cast<short*>(&h);
}
__device__ __forceinline__ float bf2f(unsigned short u) {
    return __uint_as_float((unsigned int)u << 16);
}

// ---------------- workspace layout (bytes) ----------------
// WCT 0 (49152) | BC 49152 | Z0 65536 (12.8e6) | ZA 12865536 | ZB 25665536
// DINV 38465536 | CNT 38865536 | PTR 39265536 | BSUM 39665664 | CEV 39667712
// total ~52.5 MB   (z rows padded to 64 bf16 = one 128B line)

__global__ void wct_kernel(const float* __restrict__ W1, const float* __restrict__ W2,
                           const float* __restrict__ b1, short* __restrict__ WcT,
                           float* __restrict__ bc) {
    int t = blockIdx.x * 256 + threadIdx.x;
    if (t < 48 * 512) {
        int j = t >> 9, k = t & 511;
        float s = 0.f;
        if (j < 40)
            for (int i = 0; i < 128; ++i) s = fmaf(W1[k * 128 + i], W2[i * 40 + j], s);
        WcT[j * 512 + k] = f2bf(s);
    } else if (t < 48 * 512 + 48) {
        int j = t - 48 * 512;
        float s = 0.f;
        if (j < 40)
            for (int i = 0; i < 128; ++i) s = fmaf(b1[i], W2[i * 40 + j], s);
        bc[j] = s;
    }
}

// z0 = bf16( x @ Wc + bc ), rows padded to 64 (cols 40..47 = exact zeros via WcT pad)
__global__ __launch_bounds__(256) void gemm_z0(const float* __restrict__ x,
                                               const short* __restrict__ WcT,
                                               const float* __restrict__ bc,
                                               unsigned short* __restrict__ z0) {
    const int tid = threadIdx.x;
    const int lane = tid & 63;
    const int wave = tid >> 6;
    const int rbase = blockIdx.x * 64 + wave * 16;
    const int row = rbase + (lane & 15);
    const int kc = lane >> 4;
    const bool rok = row < NN;

    f32x4 acc0 = {0.f, 0.f, 0.f, 0.f};
    f32x4 acc1 = {0.f, 0.f, 0.f, 0.f};
    f32x4 acc2 = {0.f, 0.f, 0.f, 0.f};

    const float* xrow = x + (size_t)row * 512 + kc * 8;
    const short* bp0 = WcT + (size_t)(lane & 15) * 512 + kc * 8;
    const short* bp1 = bp0 + 16 * 512;
    const short* bp2 = bp0 + 32 * 512;

    for (int k0 = 0; k0 < 512; k0 += 32) {
        float4 p0 = {0.f, 0.f, 0.f, 0.f}, p1 = {0.f, 0.f, 0.f, 0.f};
        if (rok) {
            p0 = *reinterpret_cast<const float4*>(xrow + k0);
            p1 = *reinterpret_cast<const float4*>(xrow + k0 + 4);
        }
        short8 a;
        a[0] = f2bf(p0.x); a[1] = f2bf(p0.y); a[2] = f2bf(p0.z); a[3] = f2bf(p0.w);
        a[4] = f2bf(p1.x); a[5] = f2bf(p1.y); a[6] = f2bf(p1.z); a[7] = f2bf(p1.w);
        short8 b0 = *reinterpret_cast<const short8*>(bp0 + k0);
        short8 b1 = *reinterpret_cast<const short8*>(bp1 + k0);
        short8 b2 = *reinterpret_cast<const short8*>(bp2 + k0);
        acc0 = __builtin_amdgcn_mfma_f32_16x16x32_bf16(a, b0, acc0, 0, 0, 0);
        acc1 = __builtin_amdgcn_mfma_f32_16x16x32_bf16(a, b1, acc1, 0, 0, 0);
        acc2 = __builtin_amdgcn_mfma_f32_16x16x32_bf16(a, b2, acc2, 0, 0, 0);
    }

    const int cb = lane & 15;
    const int rr = rbase + (lane >> 4) * 4;
#pragma unroll
    for (int q = 0; q < 4; ++q) {
        int r = rr + q;
        if (r < NN) {
            z0[(size_t)r * 64 + cb] = (unsigned short)f2bf(acc0[q] + bc[cb]);
            z0[(size_t)r * 64 + cb + 16] = (unsigned short)f2bf(acc1[q] + bc[cb + 16]);
            z0[(size_t)r * 64 + cb + 32] = (unsigned short)f2bf(acc2[q] + bc[cb + 32]);
        }
    }
}

__global__ void count_kernel(const int* __restrict__ eidx, int* __restrict__ counts) {
    int e = blockIdx.x * 256 + threadIdx.x;
    if (e < EE) atomicAdd(&counts[eidx[EE + e]], 1);
}

__global__ void scan1(const int* __restrict__ counts, int* __restrict__ ptr,
                      int* __restrict__ bsum) {
    __shared__ int s[256];
    int tid = threadIdx.x;
    int i = blockIdx.x * 256 + tid;
    int v = (i < NN) ? counts[i] : 0;
    s[tid] = v;
    __syncthreads();
    for (int off = 1; off < 256; off <<= 1) {
        int t = (tid >= off) ? s[tid - off] : 0;
        __syncthreads();
        s[tid] += t;
        __syncthreads();
    }
    if (i < NN) ptr[i] = s[tid] - v;
    if (tid == 255) bsum[blockIdx.x] = s[255];
}

__global__ void scan2(int* __restrict__ bsum) {
    __shared__ int s[512];
    int tid = threadIdx.x;
    int v = (tid < 391) ? bsum[tid] : 0;
    s[tid] = v;
    __syncthreads();
    for (int off = 1; off < 512; off <<= 1) {
        int t = (tid >= off) ? s[tid - off] : 0;
        __syncthreads();
        s[tid] += t;
        __syncthreads();
    }
    if (tid < 391) bsum[tid] = s[tid] - v;
}

// + fused dinv
__global__ void scan3(int* __restrict__ ptr, const int* __restrict__ bsum,
                      const int* __restrict__ counts, float* __restrict__ dinvp) {
    int i = blockIdx.x * 256 + threadIdx.x;
    if (i < NN) {
        ptr[i] += bsum[blockIdx.x];
        dinvp[i] = rsqrtf(1.0f + (float)counts[i]);
    }
    if (i == 0) ptr[NN] = EE;
}

__global__ void scatter_kernel(const int* __restrict__ eidx, const int* __restrict__ ptr,
                               const float* __restrict__ dinvp, int* __restrict__ cursor,
                               int2* __restrict__ cev) {
    int e = blockIdx.x * 256 + threadIdx.x;
    if (e < EE) {
        int r = eidx[e];
        int c = eidx[EE + e];
        int pos = ptr[c] + atomicAdd(&cursor[c], 1);
        cev[pos] = make_int2(r, __float_as_int(dinvp[r]));
    }
}

// 2 nodes per wave, software-pipelined; z rows = one 128B line each
__global__ __launch_bounds__(256) void propagate(const unsigned short* __restrict__ zcur,
                                                 const unsigned short* __restrict__ z0q,
                                                 unsigned short* __restrict__ znb,
                                                 float* __restrict__ outf,
                                                 const int* __restrict__ ptr,
                                                 const int2* __restrict__ cev,
                                                 const float* __restrict__ dinvp,
                                                 const float* __restrict__ b2, int last) {
    const int lane = threadIdx.x & 63;
    const int wid = blockIdx.x * 4 + (threadIdx.x >> 6);
    const int n0 = wid, n1 = wid + HALFN;

    const int beg0 = ptr[n0], end0 = ptr[n0 + 1];
    const int beg1 = ptr[n1], end1 = ptr[n1 + 1];
    const float dc0 = dinvp[n0], dc1 = dinvp[n1];

    // issue all independent loads up front
    int m0 = end0 - beg0; if (m0 > 64) m0 = 64;
    int m1 = end1 - beg1; if (m1 > 64) m1 = 64;
    int2 ev0 = make_int2(0, 0), ev1 = make_int2(0, 0);
    if (m0 > 0) ev0 = cev[beg0 + (lane < m0 ? lane : m0 - 1)];
    if (m1 > 0) ev1 = cev[beg1 + (lane < m1 ? lane : m1 - 1)];
    const float self0 = bf2f(zcur[(size_t)n0 * 64 + lane]);
    const float self1 = bf2f(zcur[(size_t)n1 * 64 + lane]);
    const float z00 = bf2f(z0q[(size_t)n0 * 64 + lane]);
    const float z01 = bf2f(z0q[(size_t)n1 * 64 + lane]);

    auto run_node = [&](int beg, int end, int2 ev, int m, float accInit) -> float {
        float a = accInit, b = 0.f;
        int e = beg;
        while (m > 0) {
            int rl = ev.x, vl = ev.y;
            int j = 0;
            for (; j + 4 <= m; j += 4) {
                int r0 = __builtin_amdgcn_readlane(rl, j + 0);
                int r1 = __builtin_amdgcn_readlane(rl, j + 1);
                int r2 = __builtin_amdgcn_readlane(rl, j + 2);
                int r3 = __builtin_amdgcn_readlane(rl, j + 3);
                float x0 = bf2f(zcur[(size_t)r0 * 64 + lane]);
                float x1 = bf2f(zcur[(size_t)r1 * 64 + lane]);
                float x2 = bf2f(zcur[(size_t)r2 * 64 + lane]);
                float x3 = bf2f(zcur[(size_t)r3 * 64 + lane]);
                float v0 = __int_as_float(__builtin_amdgcn_readlane(vl, j + 0));
                float v1 = __int_as_float(__builtin_amdgcn_readlane(vl, j + 1));
                float v2 = __int_as_float(__builtin_amdgcn_readlane(vl, j + 2));
                float v3 = __int_as_float(__builtin_amdgcn_readlane(vl, j + 3));
                a = fmaf(v0, x0, a);
                b = fmaf(v1, x1, b);
                a = fmaf(v2, x2, a);
                b = fmaf(v3, x3, b);
            }
            for (; j < m; ++j) {
                int r = __builtin_amdgcn_readlane(rl, j);
                float v = __int_as_float(__builtin_amdgcn_readlane(vl, j));
                a = fmaf(v, bf2f(zcur[(size_t)r * 64 + lane]), a);
            }
            e += m;
            m = end - e;
            if (m > 64) m = 64;
            if (m > 0) ev = cev[e + (lane < m ? lane : m - 1)];
        }
        return a + b;
    };

    float s0 = run_node(beg0, end0, ev0, m0, dc0 * self0);
    float res0 = 0.5f * dc0 * s0 + 0.5f * z00;
    if (last) {
        if (lane < 40) outf[(size_t)n0 * 40 + lane] = res0 + b2[lane];
    } else {
        znb[(size_t)n0 * 64 + lane] = (unsigned short)f2bf(res0);
    }

    float s1 = run_node(beg1, end1, ev1, m1, dc1 * self1);
    float res1 = 0.5f * dc1 * s1 + 0.5f * z01;
    if (last) {
        if (lane < 40) outf[(size_t)n1 * 40 + lane] = res1 + b2[lane];
    } else {
        znb[(size_t)n1 * 64 + lane] = (unsigned short)f2bf(res1);
    }
}

extern "C" void kernel_launch(void* const* d_in, const int* in_sizes, int n_in,
                              void* d_out, int out_size, void* d_ws, size_t ws_size,
                              hipStream_t stream) {
    const float* x  = (const float*)d_in[0];
    const int*   ei = (const int*)d_in[1];
    const float* W1 = (const float*)d_in[2];
    const float* b1 = (const float*)d_in[3];
    const float* W2 = (const float*)d_in[4];
    const float* b2 = (const float*)d_in[5];
    float* out = (float*)d_out;

    char* ws = (char*)d_ws;
    short*          WcT  = (short*)(ws + 0);
    float*          bc   = (float*)(ws + 49152);
    unsigned short* z0   = (unsigned short*)(ws + 65536);
    unsigned short* za   = (unsigned short*)(ws + 12865536);
    unsigned short* zb   = (unsigned short*)(ws + 25665536);
    float*          dinv = (float*)(ws + 38465536);
    int*            cnt  = (int*)(ws + 38865536);
    int*            ptr  = (int*)(ws + 39265536);
    int*            bsum = (int*)(ws + 39665664);
    int2*           cev  = (int2*)(ws + 39667712);

    hipMemsetAsync(cnt, 0, NN * sizeof(int), stream);
    wct_kernel<<<97, 256, 0, stream>>>(W1, W2, b1, WcT, bc);
    count_kernel<<<(EE + 255) / 256, 256, 0, stream>>>(ei, cnt);
    scan1<<<391, 256, 0, stream>>>(cnt, ptr, bsum);
    scan2<<<1, 512, 0, stream>>>(bsum);
    scan3<<<391, 256, 0, stream>>>(ptr, bsum, cnt, dinv);
    gemm_z0<<<1563, 256, 0, stream>>>(x, WcT, bc, z0);
    hipMemsetAsync(cnt, 0, NN * sizeof(int), stream);
    scatter_kernel<<<(EE + 255) / 256, 256, 0, stream>>>(ei, ptr, dinv, cnt, cev);

    propagate<<<12500, 256, 0, stream>>>(z0, z0, zb, out, ptr, cev, dinv, b2, 0);
    propagate<<<12500, 256, 0, stream>>>(zb, z0, za, out, ptr, cev, dinv, b2, 0);
    propagate<<<12500, 256, 0, stream>>>(za, z0, zb, out, ptr, cev, dinv, b2, 0);
    propagate<<<12500, 256, 0, stream>>>(zb, z0, za, out, ptr, cev, dinv, b2, 0);
    propagate<<<12500, 256, 0, stream>>>(za, z0, zb, out, ptr, cev, dinv, b2, 1);
}

// Round 6
// 426.788 us; speedup vs baseline: 1.5817x; 1.0996x over previous
//
#include <hip/hip_runtime.h>
#include <hip/hip_bf16.h>

#define NN 100000
#define EE 1600000
#define HALFN 50000

typedef __attribute__((ext_vector_type(8))) short short8;
typedef __attribute__((ext_vector_type(4))) float f32x4;

__device__ __forceinline__ short f2bf(float f) {
    __hip_bfloat16 h = __float2bfloat16(f);
    return *reinterpret_cast<short*>(&h);
}
__device__ __forceinline__ float bf2f(unsigned short u) {
    return __uint_as_float((unsigned int)u << 16);
}

// ---------------- workspace layout (bytes) ----------------
// WCT 0 (49152) | BC 49152 | Z0 65536 (12.8e6) | ZA 12865536 | ZB 25665536
// DINV 38465536 | CNT 38865536 | PTR 39265536 | BSUM 39665664 | PTR2 39667712
// CEV 40067840 | total ~52.9 MB   (z rows padded to 64 bf16 = one 128B line)

__global__ void wct_kernel(const float* __restrict__ W1, const float* __restrict__ W2,
                           const float* __restrict__ b1, short* __restrict__ WcT,
                           float* __restrict__ bc) {
    int t = blockIdx.x * 256 + threadIdx.x;
    if (t < 48 * 512) {
        int j = t >> 9, k = t & 511;
        float s = 0.f;
        if (j < 40)
            for (int i = 0; i < 128; ++i) s = fmaf(W1[k * 128 + i], W2[i * 40 + j], s);
        WcT[j * 512 + k] = f2bf(s);
    } else if (t < 48 * 512 + 48) {
        int j = t - 48 * 512;
        float s = 0.f;
        if (j < 40)
            for (int i = 0; i < 128; ++i) s = fmaf(b1[i], W2[i * 40 + j], s);
        bc[j] = s;
    }
}

// z0 = bf16( x @ Wc + bc ), rows padded to 64 (cols 40..47 exact zeros via WcT pad)
__global__ __launch_bounds__(256) void gemm_z0(const float* __restrict__ x,
                                               const short* __restrict__ WcT,
                                               const float* __restrict__ bc,
                                               unsigned short* __restrict__ z0) {
    const int tid = threadIdx.x;
    const int lane = tid & 63;
    const int wave = tid >> 6;
    const int rbase = blockIdx.x * 64 + wave * 16;
    const int row = rbase + (lane & 15);
    const int kc = lane >> 4;
    const bool rok = row < NN;

    f32x4 acc0 = {0.f, 0.f, 0.f, 0.f};
    f32x4 acc1 = {0.f, 0.f, 0.f, 0.f};
    f32x4 acc2 = {0.f, 0.f, 0.f, 0.f};

    const float* xrow = x + (size_t)row * 512 + kc * 8;
    const short* bp0 = WcT + (size_t)(lane & 15) * 512 + kc * 8;
    const short* bp1 = bp0 + 16 * 512;
    const short* bp2 = bp0 + 32 * 512;

    for (int k0 = 0; k0 < 512; k0 += 32) {
        float4 p0 = {0.f, 0.f, 0.f, 0.f}, p1 = {0.f, 0.f, 0.f, 0.f};
        if (rok) {
            p0 = *reinterpret_cast<const float4*>(xrow + k0);
            p1 = *reinterpret_cast<const float4*>(xrow + k0 + 4);
        }
        short8 a;
        a[0] = f2bf(p0.x); a[1] = f2bf(p0.y); a[2] = f2bf(p0.z); a[3] = f2bf(p0.w);
        a[4] = f2bf(p1.x); a[5] = f2bf(p1.y); a[6] = f2bf(p1.z); a[7] = f2bf(p1.w);
        short8 b0 = *reinterpret_cast<const short8*>(bp0 + k0);
        short8 b1 = *reinterpret_cast<const short8*>(bp1 + k0);
        short8 b2 = *reinterpret_cast<const short8*>(bp2 + k0);
        acc0 = __builtin_amdgcn_mfma_f32_16x16x32_bf16(a, b0, acc0, 0, 0, 0);
        acc1 = __builtin_amdgcn_mfma_f32_16x16x32_bf16(a, b1, acc1, 0, 0, 0);
        acc2 = __builtin_amdgcn_mfma_f32_16x16x32_bf16(a, b2, acc2, 0, 0, 0);
    }

    const int cb = lane & 15;
    const int rr = rbase + (lane >> 4) * 4;
#pragma unroll
    for (int q = 0; q < 4; ++q) {
        int r = rr + q;
        if (r < NN) {
            z0[(size_t)r * 64 + cb] = (unsigned short)f2bf(acc0[q] + bc[cb]);
            z0[(size_t)r * 64 + cb + 16] = (unsigned short)f2bf(acc1[q] + bc[cb + 16]);
            z0[(size_t)r * 64 + cb + 32] = (unsigned short)f2bf(acc2[q] + bc[cb + 32]);
        }
    }
}

__global__ void count_kernel(const int* __restrict__ eidx, int* __restrict__ counts) {
    int e = blockIdx.x * 256 + threadIdx.x;
    if (e < EE) atomicAdd(&counts[eidx[EE + e]], 1);
}

__global__ void scan1(const int* __restrict__ counts, int* __restrict__ ptr,
                      int* __restrict__ bsum) {
    __shared__ int s[256];
    int tid = threadIdx.x;
    int i = blockIdx.x * 256 + tid;
    int v = (i < NN) ? counts[i] : 0;
    s[tid] = v;
    __syncthreads();
    for (int off = 1; off < 256; off <<= 1) {
        int t = (tid >= off) ? s[tid - off] : 0;
        __syncthreads();
        s[tid] += t;
        __syncthreads();
    }
    if (i < NN) ptr[i] = s[tid] - v;
    if (tid == 255) bsum[blockIdx.x] = s[255];
}

__global__ void scan2(int* __restrict__ bsum) {
    __shared__ int s[512];
    int tid = threadIdx.x;
    int v = (tid < 391) ? bsum[tid] : 0;
    s[tid] = v;
    __syncthreads();
    for (int off = 1; off < 512; off <<= 1) {
        int t = (tid >= off) ? s[tid - off] : 0;
        __syncthreads();
        s[tid] += t;
        __syncthreads();
    }
    if (tid < 391) bsum[tid] = s[tid] - v;
}

// finalize ptr, duplicate into ptr2 (scatter cursor), fused dinv
__global__ void scan3(int* __restrict__ ptr, const int* __restrict__ bsum,
                      const int* __restrict__ counts, float* __restrict__ dinvp,
                      int* __restrict__ ptr2) {
    int i = blockIdx.x * 256 + threadIdx.x;
    if (i < NN) {
        int p = ptr[i] + bsum[blockIdx.x];
        ptr[i] = p;
        ptr2[i] = p;
        dinvp[i] = rsqrtf(1.0f + (float)counts[i]);
    }
    if (i == 0) { ptr[NN] = EE; ptr2[NN] = EE; }
}

// ptr2 doubles as the atomic cursor: pos = ptr2[c]++
__global__ void scatter_kernel(const int* __restrict__ eidx,
                               const float* __restrict__ dinvp, int* __restrict__ ptr2,
                               int2* __restrict__ cev) {
    int e = blockIdx.x * 256 + threadIdx.x;
    if (e < EE) {
        int r = eidx[e];
        int c = eidx[EE + e];
        int pos = atomicAdd(&ptr2[c], 1);
        cev[pos] = make_int2(r, __float_as_int(dinvp[r]));
    }
}

// 2 nodes per wave; branch-free chunks of 8 edges per node, 16 gathers in flight
__global__ __launch_bounds__(256) void propagate(const unsigned short* __restrict__ zcur,
                                                 const unsigned short* __restrict__ z0q,
                                                 unsigned short* __restrict__ znb,
                                                 float* __restrict__ outf,
                                                 const int* __restrict__ ptr,
                                                 const int2* __restrict__ cev,
                                                 const float* __restrict__ dinvp,
                                                 const float* __restrict__ b2, int last) {
    const int lane = threadIdx.x & 63;
    const int wid = blockIdx.x * 4 + (threadIdx.x >> 6);
    const int n0 = wid, n1 = wid + HALFN;

    int beg0 = __builtin_amdgcn_readfirstlane(ptr[n0]);
    int end0 = __builtin_amdgcn_readfirstlane(ptr[n0 + 1]);
    int beg1 = __builtin_amdgcn_readfirstlane(ptr[n1]);
    int end1 = __builtin_amdgcn_readfirstlane(ptr[n1 + 1]);
    const float dc0 = dinvp[n0], dc1 = dinvp[n1];

    int m0 = end0 - beg0; if (m0 > 64) m0 = 64;
    int m1 = end1 - beg1; if (m1 > 64) m1 = 64;

    // batch loads: rows clamped to a valid entry, weights zeroed for lanes >= m
    int idx0 = beg0 + (lane < m0 ? lane : m0 - 1); if (idx0 < 0) idx0 = 0;
    int idx1 = beg1 + (lane < m1 ? lane : m1 - 1); if (idx1 < 0) idx1 = 0;
    int2 ev0 = cev[idx0];
    int2 ev1 = cev[idx1];
    if (lane >= m0) ev0.y = 0;
    if (lane >= m1) ev1.y = 0;

    const float self0 = bf2f(zcur[(size_t)n0 * 64 + lane]);
    const float self1 = bf2f(zcur[(size_t)n1 * 64 + lane]);
    const float z00 = bf2f(z0q[(size_t)n0 * 64 + lane]);
    const float z01 = bf2f(z0q[(size_t)n1 * 64 + lane]);

    float A0 = dc0 * self0, B0 = 0.f;
    float A1 = dc1 * self1, B1 = 0.f;

    int nc0 = (m0 + 7) >> 3, nc1 = (m1 + 7) >> 3;
    int nc = nc0 > nc1 ? nc0 : nc1;
    for (int c = 0; c < nc; ++c) {
        const int j = c * 8;
        float x[8], y[8];
#pragma unroll
        for (int k = 0; k < 8; ++k) {
            int r0 = __builtin_amdgcn_readlane(ev0.x, j + k);
            int r1 = __builtin_amdgcn_readlane(ev1.x, j + k);
            x[k] = bf2f(zcur[(size_t)r0 * 64 + lane]);
            y[k] = bf2f(zcur[(size_t)r1 * 64 + lane]);
        }
#pragma unroll
        for (int k = 0; k < 8; ++k) {
            float w = __int_as_float(__builtin_amdgcn_readlane(ev0.y, j + k));
            float u = __int_as_float(__builtin_amdgcn_readlane(ev1.y, j + k));
            if (k & 1) { B0 = fmaf(w, x[k], B0); B1 = fmaf(u, y[k], B1); }
            else       { A0 = fmaf(w, x[k], A0); A1 = fmaf(u, y[k], A1); }
        }
    }

    // ultra-rare tail: degree > 64
    for (int e = beg0 + 64; e < end0; ++e) {
        int2 ee = cev[e];
        A0 = fmaf(__int_as_float(ee.y), bf2f(zcur[(size_t)ee.x * 64 + lane]), A0);
    }
    for (int e = beg1 + 64; e < end1; ++e) {
        int2 ee = cev[e];
        A1 = fmaf(__int_as_float(ee.y), bf2f(zcur[(size_t)ee.x * 64 + lane]), A1);
    }

    float res0 = 0.5f * dc0 * (A0 + B0) + 0.5f * z00;
    float res1 = 0.5f * dc1 * (A1 + B1) + 0.5f * z01;
    if (last) {
        if (lane < 40) {
            outf[(size_t)n0 * 40 + lane] = res0 + b2[lane];
            outf[(size_t)n1 * 40 + lane] = res1 + b2[lane];
        }
    } else {
        znb[(size_t)n0 * 64 + lane] = (unsigned short)f2bf(res0);
        znb[(size_t)n1 * 64 + lane] = (unsigned short)f2bf(res1);
    }
}

extern "C" void kernel_launch(void* const* d_in, const int* in_sizes, int n_in,
                              void* d_out, int out_size, void* d_ws, size_t ws_size,
                              hipStream_t stream) {
    const float* x  = (const float*)d_in[0];
    const int*   ei = (const int*)d_in[1];
    const float* W1 = (const float*)d_in[2];
    const float* b1 = (const float*)d_in[3];
    const float* W2 = (const float*)d_in[4];
    const float* b2 = (const float*)d_in[5];
    float* out = (float*)d_out;

    char* ws = (char*)d_ws;
    short*          WcT  = (short*)(ws + 0);
    float*          bc   = (float*)(ws + 49152);
    unsigned short* z0   = (unsigned short*)(ws + 65536);
    unsigned short* za   = (unsigned short*)(ws + 12865536);
    unsigned short* zb   = (unsigned short*)(ws + 25665536);
    float*          dinv = (float*)(ws + 38465536);
    int*            cnt  = (int*)(ws + 38865536);
    int*            ptr  = (int*)(ws + 39265536);
    int*            bsum = (int*)(ws + 39665664);
    int*            ptr2 = (int*)(ws + 39667712);
    int2*           cev  = (int2*)(ws + 40067840);

    hipMemsetAsync(cnt, 0, NN * sizeof(int), stream);
    wct_kernel<<<97, 256, 0, stream>>>(W1, W2, b1, WcT, bc);
    count_kernel<<<(EE + 255) / 256, 256, 0, stream>>>(ei, cnt);
    scan1<<<391, 256, 0, stream>>>(cnt, ptr, bsum);
    scan2<<<1, 512, 0, stream>>>(bsum);
    scan3<<<391, 256, 0, stream>>>(ptr, bsum, cnt, dinv, ptr2);
    gemm_z0<<<1563, 256, 0, stream>>>(x, WcT, bc, z0);
    scatter_kernel<<<(EE + 255) / 256, 256, 0, stream>>>(ei, dinv, ptr2, cev);

    propagate<<<12500, 256, 0, stream>>>(z0, z0, zb, out, ptr, cev, dinv, b2, 0);
    propagate<<<12500, 256, 0, stream>>>(zb, z0, za, out, ptr, cev, dinv, b2, 0);
    propagate<<<12500, 256, 0, stream>>>(za, z0, zb, out, ptr, cev, dinv, b2, 0);
    propagate<<<12500, 256, 0, stream>>>(zb, z0, za, out, ptr, cev, dinv, b2, 0);
    propagate<<<12500, 256, 0, stream>>>(za, z0, zb, out, ptr, cev, dinv, b2, 1);
}